// Round 1
// baseline (374.152 us; speedup 1.0000x reference)
//
#include <hip/hip_runtime.h>

#define HC 60
#define WCC 80
#define NCELL 4800
#define NP 4864          // padded to 38*128
#define DCH 256
#define BATCH 2

typedef _Float16 half8 __attribute__((ext_vector_type(8)));
typedef float f32x4 __attribute__((ext_vector_type(4)));

__device__ __forceinline__ void gload_lds16(const void* gp, void* lp) {
  __builtin_amdgcn_global_load_lds(
      (const __attribute__((address_space(1))) void*)gp,
      (__attribute__((address_space(3))) void*)lp, 16, 0, 0);
}

// ---------------- warp coords: (row,col) of warped cell centers -------------
__global__ __launch_bounds__(256) void warp_kernel(const float* __restrict__ H,
                                                   float* __restrict__ wout) {
  int idx = blockIdx.x * 256 + threadIdx.x;
  if (idx >= BATCH * NP) return;
  int b = idx / NP;
  int q = idx - b * NP;
  float wr = 1e9f, wc = 1e9f;   // padded cells: push far away -> S=0
  if (q < NCELL) {
    int i = q / WCC;
    int j = q - i * WCC;
    float x = (float)(j * 8 + 4);
    float y = (float)(i * 8 + 4);
    const float* h = H + b * 9;
    float w0 = h[0] * x + h[1] * y + h[2];
    float w1 = h[3] * x + h[4] * y + h[5];
    float w2 = h[6] * x + h[7] * y + h[8];
    wr = w1 / w2;   // row = y'
    wc = w0 / w2;   // col = x'
  }
  wout[2 * idx]     = wr;
  wout[2 * idx + 1] = wc;
}

// ------------- normalize + transpose (b,d,hc,wc) -> padded (b,NP,d) f16 -----
__global__ __launch_bounds__(256) void normalize_kernel(
    const float* __restrict__ desc, const float* __restrict__ wdesc,
    _Float16* __restrict__ dnp, _Float16* __restrict__ wnp) {
  const int q = blockIdx.x;       // 0..NP-1
  const int which = blockIdx.y;   // 0: desc, 1: wrap_desc
  const int b = blockIdx.z;
  const int c = threadIdx.x;      // channel 0..255
  const float* in = which ? wdesc : desc;
  _Float16* out = which ? wnp : dnp;
  float v = 0.f;
  if (q < NCELL) v = in[((size_t)b * DCH + c) * NCELL + q];
  float ss = v * v;
#pragma unroll
  for (int s = 1; s < 64; s <<= 1) ss += __shfl_xor(ss, s, 64);
  __shared__ float red[4];
  const int lane = c & 63, wv = c >> 6;
  if (lane == 0) red[wv] = ss;
  __syncthreads();
  float tot = red[0] + red[1] + red[2] + red[3];
  float inv = 1.f / fmaxf(sqrtf(tot), 1e-12f);   // matches F.normalize eps
  out[((size_t)b * NP + q) * DCH + c] = (_Float16)(v * inv);
}

// ---------------- shared GEMM core, 3 modes ---------------------------------
// MODE 0: rows=q (A=dn), accumulate r2[q] = sum_t relu(dot)^2
// MODE 1: rows=t (A=wn), cols=q, scale cols by invr[q], accumulate c2[t]
// MODE 2: rows=q, cols=t, v = u*invr[q]*invc[t], margin loss -> lossacc
template <int MODE>
__global__ __launch_bounds__(256) void gemm_kernel(
    const _Float16* __restrict__ A, const _Float16* __restrict__ Bm,
    const float* __restrict__ invr, const float* __restrict__ colscale,
    const float* __restrict__ warp, float* __restrict__ sqacc,
    double* __restrict__ lossacc) {
  __shared__ _Float16 As[128][64];   // 16 KiB
  __shared__ _Float16 Bs[128][64];   // 16 KiB
  const int tid = threadIdx.x;
  const int wave = tid >> 6;
  const int lane = tid & 63;
  const int batch = blockIdx.z;
  const int row0 = blockIdx.y * 128;
  const int col0 = blockIdx.x * 128;
  const _Float16* Ab = A + ((size_t)batch * NP + row0) * DCH;
  const _Float16* Bb = Bm + ((size_t)batch * NP + col0) * DCH;

  const int wq_r = wave >> 1;   // wave's 64-row half
  const int wq_c = wave & 1;    // wave's 64-col half
  const int g = lane >> 4;      // 0..3 (k-group / C row subgroup)
  const int cL = lane & 15;     // frag row (A/B) and C col

  f32x4 acc[4][4] = {};

  const int srow = lane >> 3;   // staging: row within 8-row chunk
  const int scol = lane & 7;    // staging: 16B unit within 128B row

  for (int ks = 0; ks < 4; ++ks) {        // K = 256 in 4 steps of 64
#pragma unroll
    for (int c = 0; c < 4; ++c) {         // each wave: 4 A-chunks + 4 B-chunks
      const int chunk = wave * 4 + c;     // 1 KiB chunk = 8 rows x 128B
      const int r = chunk * 8 + srow;
      gload_lds16(Ab + (size_t)r * DCH + ks * 64 + scol * 8,
                  (char*)(&As[0][0]) + chunk * 1024);
      gload_lds16(Bb + (size_t)r * DCH + ks * 64 + scol * 8,
                  (char*)(&Bs[0][0]) + chunk * 1024);
    }
    __syncthreads();   // drains vmcnt for global_load_lds
#pragma unroll
    for (int kk = 0; kk < 2; ++kk) {
      half8 af[4], bf[4];
#pragma unroll
      for (int m = 0; m < 4; ++m)
        af[m] = *reinterpret_cast<const half8*>(
            &As[wq_r * 64 + m * 16 + cL][kk * 32 + g * 8]);
#pragma unroll
      for (int n = 0; n < 4; ++n)
        bf[n] = *reinterpret_cast<const half8*>(
            &Bs[wq_c * 64 + n * 16 + cL][kk * 32 + g * 8]);
#pragma unroll
      for (int m = 0; m < 4; ++m)
#pragma unroll
        for (int n = 0; n < 4; ++n)
          acc[m][n] =
              __builtin_amdgcn_mfma_f32_16x16x32_f16(af[m], bf[n], acc[m][n], 0, 0, 0);
    }
    __syncthreads();
  }

  if (MODE == 0 || MODE == 1) {
    float cs[4];
    if (MODE == 1) {
#pragma unroll
      for (int n = 0; n < 4; ++n)
        cs[n] = colscale[(size_t)batch * NP + col0 + wq_c * 64 + n * 16 + cL];
    }
    float rs[4][4];
#pragma unroll
    for (int m = 0; m < 4; ++m)
#pragma unroll
      for (int j = 0; j < 4; ++j) rs[m][j] = 0.f;
#pragma unroll
    for (int m = 0; m < 4; ++m)
#pragma unroll
      for (int n = 0; n < 4; ++n)
#pragma unroll
        for (int j = 0; j < 4; ++j) {
          float u = fmaxf(acc[m][n][j], 0.f);
          if (MODE == 1) u *= cs[n];
          rs[m][j] += u * u;
        }
#pragma unroll
    for (int m = 0; m < 4; ++m)
#pragma unroll
      for (int j = 0; j < 4; ++j) {
        float v = rs[m][j];
        v += __shfl_xor(v, 1, 64);
        v += __shfl_xor(v, 2, 64);
        v += __shfl_xor(v, 4, 64);
        v += __shfl_xor(v, 8, 64);
        if (cL == 0)
          atomicAdd(&sqacc[(size_t)batch * NP + row0 + wq_r * 64 + m * 16 + g * 4 + j], v);
      }
  } else {
    float cy[4], cx[4], ic[4];
    int cvalid[4];
#pragma unroll
    for (int n = 0; n < 4; ++n) {
      int ct = col0 + wq_c * 64 + n * 16 + cL;
      cvalid[n] = (ct < NCELL);
      int tk = ct / WCC;
      int tl = ct - tk * WCC;
      cy[n] = (float)(tk * 8 + 4);
      cx[n] = (float)(tl * 8 + 4);
      ic[n] = colscale[(size_t)batch * NP + ct];
    }
    float lsum = 0.f;
#pragma unroll
    for (int m = 0; m < 4; ++m)
#pragma unroll
      for (int j = 0; j < 4; ++j) {
        const int rq = row0 + wq_r * 64 + m * 16 + g * 4 + j;
        if (rq < NCELL) {
          const float ir = invr[(size_t)batch * NP + rq];
          const float wr = warp[((size_t)batch * NP + rq) * 2];
          const float wcol = warp[((size_t)batch * NP + rq) * 2 + 1];
#pragma unroll
          for (int n = 0; n < 4; ++n) {
            if (cvalid[n]) {
              float u = fmaxf(acc[m][n][j], 0.f);
              float v = u * ir * ic[n];
              float dr = cy[n] - wr;
              float dc = cx[n] - wcol;
              float pos = 250.f * fmaxf(1.f - v, 0.f);
              float neg = fmaxf(v - 0.2f, 0.f);
              lsum += (dr * dr + dc * dc <= 56.25f) ? pos : neg;
            }
          }
        }
      }
#pragma unroll
    for (int s = 1; s < 64; s <<= 1) lsum += __shfl_xor(lsum, s, 64);
    if (lane == 0) atomicAdd(lossacc, (double)lsum);
  }
}

__global__ void finalize_inv(const float* __restrict__ sq, float* __restrict__ inv,
                             int count) {
  int i = blockIdx.x * 256 + threadIdx.x;
  if (i < count) inv[i] = 1.f / fmaxf(sqrtf(sq[i]), 1e-12f);
}

__global__ void final_out(const double* __restrict__ acc, float* __restrict__ out) {
  if (threadIdx.x == 0 && blockIdx.x == 0)
    out[0] = (float)(acc[0] / ((double)NCELL * (double)NCELL));
}

extern "C" void kernel_launch(void* const* d_in, const int* in_sizes, int n_in,
                              void* d_out, int out_size, void* d_ws, size_t ws_size,
                              hipStream_t stream) {
  const float* desc  = (const float*)d_in[0];
  const float* wdesc = (const float*)d_in[1];
  const float* H     = (const float*)d_in[2];
  char* ws = (char*)d_ws;

  constexpr size_t SZ_HALF = (size_t)BATCH * NP * DCH * sizeof(_Float16);  // ~4.75 MB
  constexpr size_t SZ_WARP = (size_t)BATCH * NP * 2 * sizeof(float);
  constexpr size_t SZ_VEC  = (size_t)BATCH * NP * sizeof(float);
  constexpr size_t OFF_DNP  = 0;
  constexpr size_t OFF_WNP  = OFF_DNP + SZ_HALF;
  constexpr size_t OFF_WARP = OFF_WNP + SZ_HALF;
  constexpr size_t OFF_R2   = OFF_WARP + SZ_WARP;
  constexpr size_t OFF_INVR = OFF_R2 + SZ_VEC;
  constexpr size_t OFF_C2   = OFF_INVR + SZ_VEC;
  constexpr size_t OFF_INVC = OFF_C2 + SZ_VEC;
  constexpr size_t OFF_ACC  = OFF_INVC + SZ_VEC;

  _Float16* dnp = (_Float16*)(ws + OFF_DNP);
  _Float16* wnp = (_Float16*)(ws + OFF_WNP);
  float* warp = (float*)(ws + OFF_WARP);
  float* r2   = (float*)(ws + OFF_R2);
  float* invr = (float*)(ws + OFF_INVR);
  float* c2   = (float*)(ws + OFF_C2);
  float* invc = (float*)(ws + OFF_INVC);
  double* acc = (double*)(ws + OFF_ACC);

  hipMemsetAsync(r2, 0, SZ_VEC, stream);
  hipMemsetAsync(c2, 0, SZ_VEC, stream);
  hipMemsetAsync(acc, 0, sizeof(double), stream);

  warp_kernel<<<dim3((BATCH * NP + 255) / 256), 256, 0, stream>>>(H, warp);
  normalize_kernel<<<dim3(NP, 2, BATCH), 256, 0, stream>>>(desc, wdesc, dnp, wnp);

  dim3 gg(NP / 128, NP / 128, BATCH);
  gemm_kernel<0><<<gg, 256, 0, stream>>>(dnp, wnp, nullptr, nullptr, nullptr, r2, nullptr);
  finalize_inv<<<(BATCH * NP + 255) / 256, 256, 0, stream>>>(r2, invr, BATCH * NP);
  gemm_kernel<1><<<gg, 256, 0, stream>>>(wnp, dnp, nullptr, invr, nullptr, c2, nullptr);
  finalize_inv<<<(BATCH * NP + 255) / 256, 256, 0, stream>>>(c2, invc, BATCH * NP);
  gemm_kernel<2><<<gg, 256, 0, stream>>>(dnp, wnp, invr, invc, warp, nullptr, acc);
  final_out<<<1, 64, 0, stream>>>(acc, (float*)d_out);
}

// Round 2
// 250.482 us; speedup vs baseline: 1.4937x; 1.4937x over previous
//
#include <hip/hip_runtime.h>

#define HC 60
#define WCC 80
#define NCELL 4800
#define NP 4864          // padded to 38*128
#define NB 38            // NP/128
#define DCH 256
#define BATCH 2
#define QT 64

typedef _Float16 half8 __attribute__((ext_vector_type(8)));
typedef float f32x4 __attribute__((ext_vector_type(4)));

__device__ __forceinline__ void gload_lds16(const void* gp, void* lp) {
  __builtin_amdgcn_global_load_lds(
      (const __attribute__((address_space(1))) void*)gp,
      (__attribute__((address_space(3))) void*)lp, 16, 0, 0);
}

// ---------------- warp coords: (row,col) of warped cell centers -------------
__global__ __launch_bounds__(256) void warp_kernel(const float* __restrict__ H,
                                                   float* __restrict__ wout) {
  int idx = blockIdx.x * 256 + threadIdx.x;
  if (idx >= BATCH * NP) return;
  int b = idx / NP;
  int q = idx - b * NP;
  float wr = 1e9f, wc = 1e9f;   // padded cells: push far away -> S=0
  if (q < NCELL) {
    int i = q / WCC;
    int j = q - i * WCC;
    float x = (float)(j * 8 + 4);
    float y = (float)(i * 8 + 4);
    const float* h = H + b * 9;
    float w0 = h[0] * x + h[1] * y + h[2];
    float w1 = h[3] * x + h[4] * y + h[5];
    float w2 = h[6] * x + h[7] * y + h[8];
    wr = w1 / w2;
    wc = w0 / w2;
  }
  wout[2 * idx]     = wr;
  wout[2 * idx + 1] = wc;
}

// ------ normalize + transpose (b,d,hc,wc) -> padded (b,NP,d) f16, coalesced --
__global__ __launch_bounds__(256) void normalize_kernel(
    const float* __restrict__ desc, const float* __restrict__ wdesc,
    _Float16* __restrict__ dnp, _Float16* __restrict__ wnp) {
  __shared__ _Float16 vt[DCH][QT + 2];   // +2 halfs pad -> read stride 33 dwords
  __shared__ float pss[4][QT];
  __shared__ float invq[QT];
  const int q0 = blockIdx.x * QT;        // 76 tiles cover NP
  const int which = blockIdx.y;
  const int b = blockIdx.z;
  const float* in = which ? wdesc : desc;
  _Float16* out = which ? wnp : dnp;
  const int tx = threadIdx.x & 63;       // q within tile
  const int ty = threadIdx.x >> 6;       // channel subgroup
  const int q = q0 + tx;
  float ss = 0.f;
  for (int cc = 0; cc < DCH / 4; ++cc) {
    const int c = cc * 4 + ty;
    float v = (q < NCELL) ? in[((size_t)b * DCH + c) * NCELL + q] : 0.f;
    vt[c][tx] = (_Float16)v;
    ss += v * v;
  }
  pss[ty][tx] = ss;
  __syncthreads();
  if (ty == 0) {
    float tot = pss[0][tx] + pss[1][tx] + pss[2][tx] + pss[3][tx];
    invq[tx] = 1.f / fmaxf(sqrtf(tot), 1e-12f);   // matches F.normalize eps
  }
  __syncthreads();
  for (int it = 0; it < QT; ++it) {
    out[((size_t)b * NP + q0 + it) * DCH + threadIdx.x] =
        (_Float16)((float)vt[threadIdx.x][it] * invq[it]);
  }
}

// ---------------- shared GEMM core, 3 modes ---------------------------------
// MODE 0: rows=q (A=dn), accumulate r2[q] = sum_t relu(dot)^2
// MODE 1: rows=t (A=wn), cols=q, scale cols by invr[q], accumulate c2[t]
// MODE 2: rows=q, cols=t, v = u*invr[q]*invc[t], margin loss -> lossp slots
template <int MODE>
__global__ __launch_bounds__(256) void gemm_kernel(
    const _Float16* __restrict__ A, const _Float16* __restrict__ Bm,
    const float* __restrict__ invr, const float* __restrict__ colscale,
    const float* __restrict__ warp, float* __restrict__ sqacc,
    float* __restrict__ lossp) {
  __shared__ _Float16 As[128][64];   // 16 KiB (content XOR-swizzled per row)
  __shared__ _Float16 Bs[128][64];   // 16 KiB
  const int tid = threadIdx.x;
  const int wave = tid >> 6;
  const int lane = tid & 63;
  const int batch = blockIdx.z;
  const int row0 = blockIdx.y * 128;
  const int col0 = blockIdx.x * 128;
  const _Float16* Ab = A + ((size_t)batch * NP + row0) * DCH;
  const _Float16* Bb = Bm + ((size_t)batch * NP + col0) * DCH;

  const int wq_r = wave >> 1;
  const int wq_c = wave & 1;
  const int g = lane >> 4;      // 0..3
  const int cL = lane & 15;

  f32x4 acc[4][4] = {};

  const int srow = lane >> 3;   // 0..7: row within 8-row chunk
  const int scol = lane & 7;    // 0..7: 16B unit within 128B row-slice
  const int sc_swz = (scol ^ srow) * 8;   // pre-swizzled global col (halfs)

  for (int ks = 0; ks < 4; ++ks) {        // K = 256 in 4 steps of 64
#pragma unroll
    for (int c = 0; c < 4; ++c) {
      const int chunk = wave * 4 + c;     // 1 KiB chunk = 8 rows x 128B
      const int r = chunk * 8 + srow;
      gload_lds16(Ab + (size_t)r * DCH + ks * 64 + sc_swz,
                  (char*)(&As[0][0]) + chunk * 1024);
      gload_lds16(Bb + (size_t)r * DCH + ks * 64 + sc_swz,
                  (char*)(&Bs[0][0]) + chunk * 1024);
    }
    __syncthreads();
#pragma unroll
    for (int kk = 0; kk < 2; ++kk) {
      half8 af[4], bf[4];
#pragma unroll
      for (int m = 0; m < 4; ++m) {
        const int row = wq_r * 64 + m * 16 + cL;
        const int c16 = (kk * 4 + g) ^ (row & 7);
        af[m] = *reinterpret_cast<const half8*>(
            (const char*)(&As[0][0]) + row * 128 + c16 * 16);
      }
#pragma unroll
      for (int n = 0; n < 4; ++n) {
        const int row = wq_c * 64 + n * 16 + cL;
        const int c16 = (kk * 4 + g) ^ (row & 7);
        bf[n] = *reinterpret_cast<const half8*>(
            (const char*)(&Bs[0][0]) + row * 128 + c16 * 16);
      }
#pragma unroll
      for (int m = 0; m < 4; ++m)
#pragma unroll
        for (int n = 0; n < 4; ++n)
          acc[m][n] =
              __builtin_amdgcn_mfma_f32_16x16x32_f16(af[m], bf[n], acc[m][n], 0, 0, 0);
    }
    __syncthreads();
  }

  if (MODE == 0 || MODE == 1) {
    float cs[4];
    if (MODE == 1) {
#pragma unroll
      for (int n = 0; n < 4; ++n)
        cs[n] = colscale[(size_t)batch * NP + col0 + wq_c * 64 + n * 16 + cL];
    }
    float rs[4][4];
#pragma unroll
    for (int m = 0; m < 4; ++m)
#pragma unroll
      for (int j = 0; j < 4; ++j) rs[m][j] = 0.f;
#pragma unroll
    for (int m = 0; m < 4; ++m)
#pragma unroll
      for (int n = 0; n < 4; ++n)
#pragma unroll
        for (int j = 0; j < 4; ++j) {
          float u = fmaxf(acc[m][n][j], 0.f);
          if (MODE == 1) u *= cs[n];
          rs[m][j] += u * u;
        }
#pragma unroll
    for (int m = 0; m < 4; ++m)
#pragma unroll
      for (int j = 0; j < 4; ++j) {
        float v = rs[m][j];
        v += __shfl_xor(v, 1, 64);
        v += __shfl_xor(v, 2, 64);
        v += __shfl_xor(v, 4, 64);
        v += __shfl_xor(v, 8, 64);
        if (cL == 0)
          atomicAdd(&sqacc[(size_t)batch * NP + row0 + wq_r * 64 + m * 16 + g * 4 + j], v);
      }
  } else {
    float cy[4], cx[4], ic[4];
    int cvalid[4];
#pragma unroll
    for (int n = 0; n < 4; ++n) {
      int ct = col0 + wq_c * 64 + n * 16 + cL;
      cvalid[n] = (ct < NCELL);
      int tk = ct / WCC;
      int tl = ct - tk * WCC;
      cy[n] = (float)(tk * 8 + 4);
      cx[n] = (float)(tl * 8 + 4);
      ic[n] = colscale[(size_t)batch * NP + ct];
    }
    float lsum = 0.f;
#pragma unroll
    for (int m = 0; m < 4; ++m)
#pragma unroll
      for (int j = 0; j < 4; ++j) {
        const int rq = row0 + wq_r * 64 + m * 16 + g * 4 + j;
        if (rq < NCELL) {
          const float ir = invr[(size_t)batch * NP + rq];
          const float wr = warp[((size_t)batch * NP + rq) * 2];
          const float wcol = warp[((size_t)batch * NP + rq) * 2 + 1];
#pragma unroll
          for (int n = 0; n < 4; ++n) {
            if (cvalid[n]) {
              float u = fmaxf(acc[m][n][j], 0.f);
              float v = u * ir * ic[n];
              float dr = cy[n] - wr;
              float dc = cx[n] - wcol;
              float pos = 250.f * fmaxf(1.f - v, 0.f);
              float neg = fmaxf(v - 0.2f, 0.f);
              lsum += (dr * dr + dc * dc <= 56.25f) ? pos : neg;
            }
          }
        }
      }
#pragma unroll
    for (int s = 1; s < 64; s <<= 1) lsum += __shfl_xor(lsum, s, 64);
    // one slot per wave -> no atomic contention
    if (lane == 0) {
      int slot = (((batch * NB + blockIdx.y) * NB + blockIdx.x) << 2) | wave;
      lossp[slot] = lsum;
    }
  }
}

__global__ void finalize_inv(const float* __restrict__ sq, float* __restrict__ inv,
                             int count) {
  int i = blockIdx.x * 256 + threadIdx.x;
  if (i < count) inv[i] = 1.f / fmaxf(sqrtf(sq[i]), 1e-12f);
}

__global__ __launch_bounds__(1024) void loss_reduce(const float* __restrict__ lossp,
                                                    float* __restrict__ out) {
  const int COUNT = BATCH * NB * NB * 4;
  double s = 0.0;
  for (int i = threadIdx.x; i < COUNT; i += 1024) s += (double)lossp[i];
#pragma unroll
  for (int k = 1; k < 64; k <<= 1) s += __shfl_xor(s, k, 64);
  __shared__ double sd[16];
  if ((threadIdx.x & 63) == 0) sd[threadIdx.x >> 6] = s;
  __syncthreads();
  if (threadIdx.x == 0) {
    double t = 0.0;
    for (int w = 0; w < 16; ++w) t += sd[w];
    out[0] = (float)(t / ((double)NCELL * (double)NCELL));
  }
}

extern "C" void kernel_launch(void* const* d_in, const int* in_sizes, int n_in,
                              void* d_out, int out_size, void* d_ws, size_t ws_size,
                              hipStream_t stream) {
  const float* desc  = (const float*)d_in[0];
  const float* wdesc = (const float*)d_in[1];
  const float* H     = (const float*)d_in[2];
  char* ws = (char*)d_ws;

  constexpr size_t SZ_HALF = (size_t)BATCH * NP * DCH * sizeof(_Float16);
  constexpr size_t SZ_WARP = (size_t)BATCH * NP * 2 * sizeof(float);
  constexpr size_t SZ_VEC  = (size_t)BATCH * NP * sizeof(float);
  constexpr size_t SZ_LOSS = (size_t)BATCH * NB * NB * 4 * sizeof(float);
  constexpr size_t OFF_DNP  = 0;
  constexpr size_t OFF_WNP  = OFF_DNP + SZ_HALF;
  constexpr size_t OFF_WARP = OFF_WNP + SZ_HALF;
  constexpr size_t OFF_R2   = OFF_WARP + SZ_WARP;
  constexpr size_t OFF_INVR = OFF_R2 + SZ_VEC;
  constexpr size_t OFF_C2   = OFF_INVR + SZ_VEC;
  constexpr size_t OFF_INVC = OFF_C2 + SZ_VEC;
  constexpr size_t OFF_LOSS = OFF_INVC + SZ_VEC;

  _Float16* dnp = (_Float16*)(ws + OFF_DNP);
  _Float16* wnp = (_Float16*)(ws + OFF_WNP);
  float* warp = (float*)(ws + OFF_WARP);
  float* r2   = (float*)(ws + OFF_R2);
  float* invr = (float*)(ws + OFF_INVR);
  float* c2   = (float*)(ws + OFF_C2);
  float* invc = (float*)(ws + OFF_INVC);
  float* lossp = (float*)(ws + OFF_LOSS);

  hipMemsetAsync(r2, 0, SZ_VEC, stream);
  hipMemsetAsync(c2, 0, SZ_VEC, stream);

  warp_kernel<<<dim3((BATCH * NP + 255) / 256), 256, 0, stream>>>(H, warp);
  normalize_kernel<<<dim3(NP / QT, 2, BATCH), 256, 0, stream>>>(desc, wdesc, dnp, wnp);

  dim3 gg(NB, NB, BATCH);
  gemm_kernel<0><<<gg, 256, 0, stream>>>(dnp, wnp, nullptr, nullptr, nullptr, r2, nullptr);
  finalize_inv<<<(BATCH * NP + 255) / 256, 256, 0, stream>>>(r2, invr, BATCH * NP);
  gemm_kernel<1><<<gg, 256, 0, stream>>>(wnp, dnp, nullptr, invr, nullptr, c2, nullptr);
  finalize_inv<<<(BATCH * NP + 255) / 256, 256, 0, stream>>>(c2, invc, BATCH * NP);
  gemm_kernel<2><<<gg, 256, 0, stream>>>(dnp, wnp, invr, invc, warp, nullptr, lossp);
  loss_reduce<<<1, 1024, 0, stream>>>(lossp, (float*)d_out);
}